// Round 6
// baseline (89.601 us; speedup 1.0000x reference)
//
#include <hip/hip_runtime.h>

#define B_SZ 32
#define A_SZ 64
#define P_TOTAL 16320
#define PBLK 32                 // blocks along P
#define POS_PER_BLK 512         // 256 threads x 2 positions
#define NBLOCKS (PBLK * B_SZ)   // 1024
#define INF_C 100000000.0f

// Fused: assign + giou + block partial + last-block finalize (one dispatch).
__global__ __launch_bounds__(256) void fcos_fused_kernel(
    const float* __restrict__ reg_preds,   // [B, P, 2]
    const float* __restrict__ positions,   // [B, P]
    const float* __restrict__ gt_boxes,    // [B, A, 2]
    const float* __restrict__ mi,          // [P, 2]
    float2* __restrict__ partial,          // [B_SZ * PBLK]
    unsigned int* __restrict__ cnt,        // [1] zeroed by memset node
    float* __restrict__ out)               // [1]
{
    const int b    = blockIdx.y;
    const int pblk = blockIdx.x;
    const int tid  = threadIdx.x;

    __shared__ float2 s_box[A_SZ];
    if (tid < A_SZ)
        s_box[tid] = reinterpret_cast<const float2*>(gt_boxes)[b * A_SZ + tid];
    __syncthreads();

    // Two positions per thread, both coalesced; only p1 can run off the end.
    const int p0  = pblk * POS_PER_BLK + tid;      // <= 16127 < P_TOTAL
    const int p1  = p0 + 256;
    const bool v1 = (p1 < P_TOTAL);
    const int p1c = v1 ? p1 : (P_TOTAL - 1);

    const float pos0 = positions[b * P_TOTAL + p0];
    const float pos1 = positions[b * P_TOTAL + p1c];
    const float2 mi0 = reinterpret_cast<const float2*>(mi)[p0];
    const float2 mi1 = reinterpret_cast<const float2*>(mi)[p1c];

    // dist for an invalid box: |pos - 1e8|, identical bits to reference.
    const float inv0 = fabsf(pos0 - INF_C);
    const float inv1 = fabsf(pos1 - INF_C);

    float bd0 = 3.0e38f, bd1 = 3.0e38f;
    int   ba0 = 0,       ba1 = 0;
    bool  ip0 = false,   ip1 = false;

    #pragma unroll 8
    for (int a = 0; a < A_SZ; ++a) {
        const float2 box = s_box[a];     // wave-uniform broadcast ds_read_b64
        {   // position 0
            const float l = pos0 - box.x;
            const float r = box.y - pos0;
            const float cmin = fminf(l, r);
            const float cmax = fmaxf(l, r);
            const bool valid = (cmin > 0.0f) & (cmax >= mi0.x) & (cmax < mi0.y);
            const float center = 0.5f * (l + r) + box.x;   // exact ref expr
            const float d = valid ? fabsf(pos0 - center) : inv0;
            if (d < bd0) { bd0 = d; ba0 = a; }             // strict <: first idx
            ip0 |= valid;
        }
        {   // position 1
            const float l = pos1 - box.x;
            const float r = box.y - pos1;
            const float cmin = fminf(l, r);
            const float cmax = fmaxf(l, r);
            const bool valid = (cmin > 0.0f) & (cmax >= mi1.x) & (cmax < mi1.y);
            const float center = 0.5f * (l + r) + box.x;
            const float d = valid ? fabsf(pos1 - center) : inv1;
            if (d < bd1) { bd1 = d; ba1 = a; }
            ip1 |= valid;
        }
    }

    // ---- epilogue: refetch chosen box, recompute l_t/r_t (identical rounding)
    const float2 rp0 = reinterpret_cast<const float2*>(reg_preds)[b * P_TOTAL + p0];
    const float2 rp1 = reinterpret_cast<const float2*>(reg_preds)[b * P_TOTAL + p1c];

    float contrib = 0.0f, mval = 0.0f;
    {
        const float2 bx = s_box[ba0];
        float l_t = ip0 ? (pos0 - bx.x) : 0.0f;
        float r_t = ip0 ? (bx.y - pos0) : 0.0f;
        const float ratio = fminf(l_t, r_t) / fmaxf(fmaxf(l_t, r_t), 1e-8f);
        const float cness = ip0 ? sqrtf(fmaxf(ratio, 0.0f)) : 0.0f;
        const float pmin = pos0 - rp0.x, pmax = pos0 + rp0.y;
        const float gmin = pos0 - l_t,  gmax = pos0 + r_t;
        const float overlap = fmaxf(fminf(pmax, gmax) - fmaxf(pmin, gmin), 0.0f);
        const float uni     = fmaxf((pmax - pmin + 1.0f) + (gmax - gmin + 1.0f) - overlap, 1e-4f);
        const float enclose = fmaxf(fmaxf(pmax, gmax) - fminf(pmin, gmin), 1e-4f);
        float giou = 1.0f - overlap / uni + (enclose - uni) / enclose;
        giou = fminf(fmaxf(giou, -1.0f), 1.0f) * cness;
        if (ip0) { contrib += giou; mval += 1.0f; }
    }
    {
        const float2 bx = s_box[ba1];
        float l_t = ip1 ? (pos1 - bx.x) : 0.0f;
        float r_t = ip1 ? (bx.y - pos1) : 0.0f;
        const float ratio = fminf(l_t, r_t) / fmaxf(fmaxf(l_t, r_t), 1e-8f);
        const float cness = ip1 ? sqrtf(fmaxf(ratio, 0.0f)) : 0.0f;
        const float pmin = pos1 - rp1.x, pmax = pos1 + rp1.y;
        const float gmin = pos1 - l_t,  gmax = pos1 + r_t;
        const float overlap = fmaxf(fminf(pmax, gmax) - fmaxf(pmin, gmin), 0.0f);
        const float uni     = fmaxf((pmax - pmin + 1.0f) + (gmax - gmin + 1.0f) - overlap, 1e-4f);
        const float enclose = fmaxf(fmaxf(pmax, gmax) - fminf(pmin, gmin), 1e-4f);
        float giou = 1.0f - overlap / uni + (enclose - uni) / enclose;
        giou = fminf(fmaxf(giou, -1.0f), 1.0f) * cness;
        if (ip1 & v1) { contrib += giou; mval += 1.0f; }
    }

    // ---- block reduction: 4 waves of 64 ----
    const int lane = tid & 63;
    const int wid  = tid >> 6;
    #pragma unroll
    for (int off = 32; off > 0; off >>= 1) {
        contrib += __shfl_down(contrib, off, 64);
        mval    += __shfl_down(mval,    off, 64);
    }
    __shared__ float s_c[4], s_m[4];
    if (lane == 0) { s_c[wid] = contrib; s_m[wid] = mval; }
    __syncthreads();

    __shared__ bool is_last;
    if (tid == 0) {
        float2 o;
        o.x = s_c[0] + s_c[1] + s_c[2] + s_c[3];
        o.y = s_m[0] + s_m[1] + s_m[2] + s_m[3];
        partial[b * PBLK + pblk] = o;
        __threadfence();                       // release partials (device scope)
        const unsigned old = atomicAdd(cnt, 1u);
        is_last = (old == NBLOCKS - 1);
    }
    __syncthreads();
    if (!is_last) return;

    // ---- last block: deterministic finalize ----
    __threadfence();                           // acquire all partials

    const int fb = tid >> 3;                   // video 0..31
    const int fj = tid & 7;                    // 0..7
    float s = 0.0f, n = 0.0f;
    #pragma unroll
    for (int k = fj; k < PBLK; k += 8) {
        const float2 v = partial[fb * PBLK + k];
        s += v.x; n += v.y;
    }
    #pragma unroll
    for (int off = 4; off > 0; off >>= 1) {    // reduce within each 8-lane group
        s += __shfl_down(s, off, 64);
        n += __shfl_down(n, off, 64);
    }
    __shared__ float pv[B_SZ];
    if (fj == 0) pv[fb] = (n > 0.0f) ? (2.0f * s / fmaxf(n, 1.0f)) : 0.0f;
    __syncthreads();

    if (tid < 64) {
        float v = (tid < B_SZ) ? pv[tid] : 0.0f;
        #pragma unroll
        for (int off = 16; off > 0; off >>= 1) v += __shfl_down(v, off, 64);
        if (tid == 0) out[0] = v * (1.0f / (float)B_SZ);
    }
}

extern "C" void kernel_launch(void* const* d_in, const int* in_sizes, int n_in,
                              void* d_out, int out_size, void* d_ws, size_t ws_size,
                              hipStream_t stream) {
    const float* reg_preds = (const float*)d_in[0];   // [B, P, 2]
    const float* positions = (const float*)d_in[1];   // [B, P]
    const float* gt_boxes  = (const float*)d_in[2];   // [B, A, 2]
    const float* mi        = (const float*)d_in[3];   // [P, 2]
    float* out = (float*)d_out;

    unsigned int* cnt = (unsigned int*)d_ws;                       // [1]
    float2* partial   = (float2*)((char*)d_ws + 256);              // [1024]

    hipMemsetAsync(cnt, 0, sizeof(unsigned int), stream);          // capture-safe

    dim3 grid(PBLK, B_SZ);
    fcos_fused_kernel<<<grid, 256, 0, stream>>>(
        reg_preds, positions, gt_boxes, mi, partial, cnt, out);
}

// Round 7
// 75.846 us; speedup vs baseline: 1.1814x; 1.1814x over previous
//
#include <hip/hip_runtime.h>

#define B_SZ 32
#define A_SZ 64
#define P_TOTAL 16320
#define PBLK 32                 // blocks along P
#define POS_PER_BLK 512         // 256 threads x 2 positions
#define INF_C 100000000.0f

// Main: assign + giou + block partial. Two positions per thread.
// No atomics / fences — partials consumed by a second dispatch.
__global__ __launch_bounds__(256) void fcos_main_kernel(
    const float* __restrict__ reg_preds,   // [B, P, 2]
    const float* __restrict__ positions,   // [B, P]
    const float* __restrict__ gt_boxes,    // [B, A, 2]
    const float* __restrict__ mi,          // [P, 2]
    float2* __restrict__ partial)          // [B_SZ * PBLK]
{
    const int b    = blockIdx.y;
    const int pblk = blockIdx.x;
    const int tid  = threadIdx.x;

    __shared__ float2 s_box[A_SZ];
    if (tid < A_SZ)
        s_box[tid] = reinterpret_cast<const float2*>(gt_boxes)[b * A_SZ + tid];
    __syncthreads();

    // Two positions per thread, both coalesced; only p1 can run off the end.
    const int p0  = pblk * POS_PER_BLK + tid;      // <= 16127 < P_TOTAL
    const int p1  = p0 + 256;
    const bool v1 = (p1 < P_TOTAL);
    const int p1c = v1 ? p1 : (P_TOTAL - 1);

    const float pos0 = positions[b * P_TOTAL + p0];
    const float pos1 = positions[b * P_TOTAL + p1c];
    const float2 mi0 = reinterpret_cast<const float2*>(mi)[p0];
    const float2 mi1 = reinterpret_cast<const float2*>(mi)[p1c];

    // dist for an invalid box: |pos - 1e8|, identical bits to reference.
    const float inv0 = fabsf(pos0 - INF_C);
    const float inv1 = fabsf(pos1 - INF_C);

    float bd0 = 3.0e38f, bd1 = 3.0e38f;
    int   ba0 = 0,       ba1 = 0;
    bool  ip0 = false,   ip1 = false;

    #pragma unroll 8
    for (int a = 0; a < A_SZ; ++a) {
        const float2 box = s_box[a];     // wave-uniform broadcast ds_read_b64
        {   // position 0
            const float l = pos0 - box.x;
            const float r = box.y - pos0;
            const float cmin = fminf(l, r);
            const float cmax = fmaxf(l, r);
            const bool valid = (cmin > 0.0f) & (cmax >= mi0.x) & (cmax < mi0.y);
            const float center = 0.5f * (l + r) + box.x;   // exact ref expr
            const float d = valid ? fabsf(pos0 - center) : inv0;
            if (d < bd0) { bd0 = d; ba0 = a; }             // strict <: first idx
            ip0 |= valid;
        }
        {   // position 1
            const float l = pos1 - box.x;
            const float r = box.y - pos1;
            const float cmin = fminf(l, r);
            const float cmax = fmaxf(l, r);
            const bool valid = (cmin > 0.0f) & (cmax >= mi1.x) & (cmax < mi1.y);
            const float center = 0.5f * (l + r) + box.x;
            const float d = valid ? fabsf(pos1 - center) : inv1;
            if (d < bd1) { bd1 = d; ba1 = a; }
            ip1 |= valid;
        }
    }

    // ---- epilogue: refetch chosen box, recompute l_t/r_t (identical rounding)
    const float2 rp0 = reinterpret_cast<const float2*>(reg_preds)[b * P_TOTAL + p0];
    const float2 rp1 = reinterpret_cast<const float2*>(reg_preds)[b * P_TOTAL + p1c];

    float contrib = 0.0f, mval = 0.0f;
    {
        const float2 bx = s_box[ba0];
        float l_t = ip0 ? (pos0 - bx.x) : 0.0f;
        float r_t = ip0 ? (bx.y - pos0) : 0.0f;
        const float ratio = fminf(l_t, r_t) / fmaxf(fmaxf(l_t, r_t), 1e-8f);
        const float cness = ip0 ? sqrtf(fmaxf(ratio, 0.0f)) : 0.0f;
        const float pmin = pos0 - rp0.x, pmax = pos0 + rp0.y;
        const float gmin = pos0 - l_t,  gmax = pos0 + r_t;
        const float overlap = fmaxf(fminf(pmax, gmax) - fmaxf(pmin, gmin), 0.0f);
        const float uni     = fmaxf((pmax - pmin + 1.0f) + (gmax - gmin + 1.0f) - overlap, 1e-4f);
        const float enclose = fmaxf(fmaxf(pmax, gmax) - fminf(pmin, gmin), 1e-4f);
        float giou = 1.0f - overlap / uni + (enclose - uni) / enclose;
        giou = fminf(fmaxf(giou, -1.0f), 1.0f) * cness;
        if (ip0) { contrib += giou; mval += 1.0f; }
    }
    {
        const float2 bx = s_box[ba1];
        float l_t = ip1 ? (pos1 - bx.x) : 0.0f;
        float r_t = ip1 ? (bx.y - pos1) : 0.0f;
        const float ratio = fminf(l_t, r_t) / fmaxf(fmaxf(l_t, r_t), 1e-8f);
        const float cness = ip1 ? sqrtf(fmaxf(ratio, 0.0f)) : 0.0f;
        const float pmin = pos1 - rp1.x, pmax = pos1 + rp1.y;
        const float gmin = pos1 - l_t,  gmax = pos1 + r_t;
        const float overlap = fmaxf(fminf(pmax, gmax) - fmaxf(pmin, gmin), 0.0f);
        const float uni     = fmaxf((pmax - pmin + 1.0f) + (gmax - gmin + 1.0f) - overlap, 1e-4f);
        const float enclose = fmaxf(fmaxf(pmax, gmax) - fminf(pmin, gmin), 1e-4f);
        float giou = 1.0f - overlap / uni + (enclose - uni) / enclose;
        giou = fminf(fmaxf(giou, -1.0f), 1.0f) * cness;
        if (ip1 & v1) { contrib += giou; mval += 1.0f; }
    }

    // ---- block reduction: 4 waves of 64 ----
    const int lane = tid & 63;
    const int wid  = tid >> 6;
    #pragma unroll
    for (int off = 32; off > 0; off >>= 1) {
        contrib += __shfl_down(contrib, off, 64);
        mval    += __shfl_down(mval,    off, 64);
    }
    __shared__ float s_c[4], s_m[4];
    if (lane == 0) { s_c[wid] = contrib; s_m[wid] = mval; }
    __syncthreads();

    if (tid == 0) {
        float2 o;
        o.x = s_c[0] + s_c[1] + s_c[2] + s_c[3];
        o.y = s_m[0] + s_m[1] + s_m[2] + s_m[3];
        partial[b * PBLK + pblk] = o;
    }
}

// One block, 256 threads: 8 threads per video over 32 partials, then mean.
__global__ __launch_bounds__(256) void fcos_finalize_kernel(
    const float2* __restrict__ partial,  // [B_SZ * PBLK]
    float* __restrict__ out)             // [1]
{
    const int t = threadIdx.x;           // 0..255
    const int b = t >> 3;                // 0..31
    const int j = t & 7;                 // 0..7

    float s = 0.0f, n = 0.0f;
    #pragma unroll
    for (int k = j; k < PBLK; k += 8) {  // 4 entries each
        const float2 v = partial[b * PBLK + k];
        s += v.x; n += v.y;
    }
    #pragma unroll
    for (int off = 4; off > 0; off >>= 1) {  // reduce within each 8-lane group
        s += __shfl_down(s, off, 64);
        n += __shfl_down(n, off, 64);
    }

    __shared__ float pv[B_SZ];
    if (j == 0) pv[b] = (n > 0.0f) ? (2.0f * s / fmaxf(n, 1.0f)) : 0.0f;
    __syncthreads();

    if (t < 64) {
        float v = (t < B_SZ) ? pv[t] : 0.0f;
        #pragma unroll
        for (int off = 16; off > 0; off >>= 1) v += __shfl_down(v, off, 64);
        if (t == 0) out[0] = v * (1.0f / (float)B_SZ);
    }
}

extern "C" void kernel_launch(void* const* d_in, const int* in_sizes, int n_in,
                              void* d_out, int out_size, void* d_ws, size_t ws_size,
                              hipStream_t stream) {
    const float* reg_preds = (const float*)d_in[0];   // [B, P, 2]
    const float* positions = (const float*)d_in[1];   // [B, P]
    const float* gt_boxes  = (const float*)d_in[2];   // [B, A, 2]
    const float* mi        = (const float*)d_in[3];   // [P, 2]
    float* out = (float*)d_out;
    float2* partial = (float2*)d_ws;                   // [1024] = 8 KB

    dim3 grid(PBLK, B_SZ);
    fcos_main_kernel<<<grid, 256, 0, stream>>>(reg_preds, positions, gt_boxes, mi, partial);
    fcos_finalize_kernel<<<1, 256, 0, stream>>>(partial, out);
}